// Round 6
// baseline (322.093 us; speedup 1.0000x reference)
//
#include <hip/hip_runtime.h>
#include <hip/hip_bf16.h>

// Problem constants (fixed by reference): B=4, S=2048, DIN=DOUT=4096
constexpr int GM = 8192;   // B*S rows
constexpr int GN = 4096;   // DOUT
constexpr int GK = 4096;   // DIN

constexpr int BM = 256, BN = 256, BK = 64;
constexpr int NSTEP = GK / BK;   // 64 K-steps
constexpr int IT = NSTEP / 2;    // 32 iterations, 2 K-steps each
constexpr int LDS_BYTES = 2 * (BM + BN) * BK * 2;  // 131072 = 128 KiB

using bf16x8 = __attribute__((ext_vector_type(8))) __bf16;
using f32x4  = __attribute__((ext_vector_type(4))) float;

// -------------------- prep: A = bf16(x * in_scale) --------------------
__global__ __launch_bounds__(256) void prep_x_kernel(
    const float* __restrict__ x, const float* __restrict__ iscale,
    __bf16* __restrict__ A) {
  int e = (blockIdx.x * 256 + threadIdx.x) * 8;  // 8 elems/thread
  float4 v0 = *(const float4*)(x + e);
  float4 v1 = *(const float4*)(x + e + 4);
  int k = e & (GK - 1);
  float4 s0 = *(const float4*)(iscale + k);
  float4 s1 = *(const float4*)(iscale + k + 4);
  bf16x8 o;
  o[0] = (__bf16)(v0.x * s0.x);
  o[1] = (__bf16)(v0.y * s0.y);
  o[2] = (__bf16)(v0.z * s0.z);
  o[3] = (__bf16)(v0.w * s0.w);
  o[4] = (__bf16)(v1.x * s1.x);
  o[5] = (__bf16)(v1.y * s1.y);
  o[6] = (__bf16)(v1.z * s1.z);
  o[7] = (__bf16)(v1.w * s1.w);
  *(bf16x8*)(A + e) = o;
}

// -------------------- prep: Wb = bf16(sign(W)) --------------------
__device__ inline float sgnf(float v) {
  return (float)((v > 0.f) - (v < 0.f));
}

__global__ __launch_bounds__(256) void prep_w_kernel(
    const float* __restrict__ w, __bf16* __restrict__ Wb) {
  int e = (blockIdx.x * 256 + threadIdx.x) * 8;
  float4 v0 = *(const float4*)(w + e);
  float4 v1 = *(const float4*)(w + e + 4);
  bf16x8 o;
  o[0] = (__bf16)sgnf(v0.x);
  o[1] = (__bf16)sgnf(v0.y);
  o[2] = (__bf16)sgnf(v0.z);
  o[3] = (__bf16)sgnf(v0.w);
  o[4] = (__bf16)sgnf(v1.x);
  o[5] = (__bf16)sgnf(v1.y);
  o[6] = (__bf16)sgnf(v1.z);
  o[7] = (__bf16)sgnf(v1.w);
  *(bf16x8*)(Wb + e) = o;
}

// -------------------- GEMM: C[m][n] = sum_k A[m][k]*Wb[n][k] --------------------
// 8-phase schedule, stage-clustered. 256x256 tile, BK=64, 512 threads
// (2M x 4N waves, wave tile 128x64). LDS: 2 buffers x [A0|A1|B0|B1] x 16 KiB.
// Phase layout per iteration (2 K-steps; even step buf0, odd buf1):
//   P1: 12 ds_read (av0-3,bv0-1)            | QUAD(0,0)
//   P2: 12 ds_read (av4-7,bv2-3)            | QUAD(0,2)
//   P3: stage s2:A0,A1 -> buf0 (4 loads)    | QUAD(4,0)
//   P4: stage s2:B0,B1 -> buf0 (4 loads)    | QUAD(4,2)  + vmcnt(8) + bar
//   P5..P8: mirror on buf1 / s3.
// Stage->wait distance: every half-tile is staged >=4 phases before the
// vmcnt that retires it (s1:A@prevP7,B@prevP8 waited at P4; s2:A@P3,B@P4
// waited at P8) — ~2500 cyc of cover vs ~900 cyc HBM latency, so the
// counted vmcnt(8) retires pre-drained (this was R5's stall: B halves had
// only 2 phases of cover). Region-overwrite safety: all four regions of a
// buffer are last ds_read in the 2 phases before their re-stage, and each
// wave drains reads (lgkmcnt 0) before its MFMA, hence before that phase's
// end barrier (two-barrier invariant).
// Swizzle (both sides): 16-B chunk p of row r holds K-group p^(r&7); the
// stage pre-permutes the global source column, reads XOR the chunk index.
// Verified 0 bank conflicts (R3-R5).
__device__ inline void gload16(const __bf16* g, const __bf16* l) {
  __builtin_amdgcn_global_load_lds(
      (const __attribute__((address_space(1))) void*)g,
      (__attribute__((address_space(3))) void*)l, 16, 0, 0);
}

#define PHASE_SYNC()                                    \
  __builtin_amdgcn_sched_barrier(0);                    \
  __builtin_amdgcn_s_barrier();                         \
  asm volatile("s_waitcnt lgkmcnt(0)" ::: "memory");    \
  __builtin_amdgcn_sched_barrier(0);                    \
  __builtin_amdgcn_s_setprio(1);

#define PHASE_END()                                     \
  __builtin_amdgcn_s_setprio(0);                        \
  __builtin_amdgcn_sched_barrier(0);                    \
  __builtin_amdgcn_s_barrier();

#define QUAD(AV, BV, MO, NO)                                                 \
  {                                                                          \
    _Pragma("unroll") for (int mi = 0; mi < 4; ++mi)                         \
      _Pragma("unroll") for (int ni = 0; ni < 2; ++ni)                       \
        _Pragma("unroll") for (int kk = 0; kk < 2; ++kk)                     \
            acc[(MO) + mi][(NO) + ni] =                                      \
                __builtin_amdgcn_mfma_f32_16x16x32_bf16(                     \
                    AV[mi][kk], BV[ni][kk], acc[(MO) + mi][(NO) + ni],       \
                    0, 0, 0);                                                \
  }

__global__ __launch_bounds__(512, 2) void gemm_bt(
    const __bf16* __restrict__ A, const __bf16* __restrict__ B,
    float* __restrict__ C) {
  extern __shared__ __bf16 lds[];  // 2 x 64 KiB buffers

  // Square XCD chunking (FETCH ~200 MB measured in R3-R5)
  int bid = blockIdx.x;            // 0..511
  int x = bid & 7, idx = bid >> 3;
  int brow = ((x & 3) << 3) | (idx & 7);   // 0..31
  int bcol = ((x >> 2) << 3) | (idx >> 3); // 0..15

  int tid = threadIdx.x, wid = tid >> 6, lane = tid & 63;
  int wm = wid & 1, wn = wid >> 1;         // 2M x 4N waves
  int lrow = lane & 15, lkhi = lane >> 4;

  const __bf16* Ab = A + (size_t)(brow * BM) * GK;
  const __bf16* Bb = B + (size_t)(bcol * BN) * GK;
  const __bf16* Ab1 = Ab + (size_t)128 * GK;
  const __bf16* Bb1 = Bb + (size_t)128 * GK;

  // read-side swizzled chunk offsets (bytes within the 128-B row)
  int xr = lrow & 7;
  int offk0 = (lkhi ^ xr) * 16;        // kk=0 chunk
  int offk1 = ((4 + lkhi) ^ xr) * 16;  // kk=1 chunk
  const char* ldsc = (const char*)lds;
  // fragment byte bases within a buffer (regions: A0 0, A1 16K, B0 32K, B1 48K)
  int avbase = wm * 16384 + lrow * 128;                                // +mi*2048
  int bvbase = 32768 + (wn >> 1) * 16384 + ((wn & 1) * 64 + lrow) * 128;  // +ni*2048

  // stage-side: thread t writes bytes [t*16,t*16+16) of each 8-KiB half-region
  int grow = tid >> 3;                         // row within 64-row half
  int gcol = ((tid & 7) ^ (grow & 7)) * 8;     // pre-swizzled source col (elems)

  auto STAGE = [&](const __bf16* srcbase, int kstep, int dstelem) {
    const __bf16* s = srcbase + (size_t)grow * GK + kstep * BK + gcol;
    const __bf16* d = lds + dstelem + tid * 8;
    gload16(s, d);
    gload16(s + (size_t)64 * GK, d + 4096);
  };

  f32x4 acc[8][4] = {};

  // prologue: buf0 <- step0, buf1 <- step1 (8 half-tiles, 16 loads/thread)
  STAGE(Ab, 0, 0);
  STAGE(Ab1, 0, 8192);
  STAGE(Bb, 0, 16384);
  STAGE(Bb1, 0, 24576);
  STAGE(Ab, 1, 32768);
  STAGE(Ab1, 1, 40960);
  STAGE(Bb, 1, 49152);
  STAGE(Bb1, 1, 57344);
  asm volatile("s_waitcnt vmcnt(8)" ::: "memory");  // buf0 landed; buf1 in flight
  __builtin_amdgcn_s_barrier();

  for (int i = 0; i < IT; ++i) {
    int s2 = 2 * i + 2, s3 = 2 * i + 3;
    bool full = (i < IT - 1);
    bf16x8 a0[4][2], a4[4][2], b0[2][2], b2[2][2];

    // ================= K-step 2i (buf0, byte 0) =================
    // P1: read av0-3 + bv0-1 (12 ds_read)
#pragma unroll
    for (int mi = 0; mi < 4; ++mi) {
      a0[mi][0] = *(const bf16x8*)(ldsc + avbase + mi * 2048 + offk0);
      a0[mi][1] = *(const bf16x8*)(ldsc + avbase + mi * 2048 + offk1);
    }
#pragma unroll
    for (int ni = 0; ni < 2; ++ni) {
      b0[ni][0] = *(const bf16x8*)(ldsc + bvbase + ni * 2048 + offk0);
      b0[ni][1] = *(const bf16x8*)(ldsc + bvbase + ni * 2048 + offk1);
    }
    PHASE_SYNC();
    QUAD(a0, b0, 0, 0);
    PHASE_END();

    // P2: read av4-7 + bv2-3 (12 ds_read)
#pragma unroll
    for (int mi = 0; mi < 4; ++mi) {
      a4[mi][0] = *(const bf16x8*)(ldsc + avbase + (4 + mi) * 2048 + offk0);
      a4[mi][1] = *(const bf16x8*)(ldsc + avbase + (4 + mi) * 2048 + offk1);
    }
#pragma unroll
    for (int ni = 0; ni < 2; ++ni) {
      b2[ni][0] = *(const bf16x8*)(ldsc + bvbase + (2 + ni) * 2048 + offk0);
      b2[ni][1] = *(const bf16x8*)(ldsc + bvbase + (2 + ni) * 2048 + offk1);
    }
    PHASE_SYNC();
    QUAD(a0, b2, 0, 2);
    PHASE_END();

    // P3: stage s2:A0,A1 -> buf0 (regions last read in P2)
    if (full) { STAGE(Ab, s2, 0); STAGE(Ab1, s2, 8192); }
    PHASE_SYNC();
    QUAD(a4, b0, 4, 0);
    PHASE_END();

    // P4: stage s2:B0,B1 -> buf0; counted vmcnt(8) retires s1 (prev P7/P8)
    if (full) { STAGE(Bb, s2, 16384); STAGE(Bb1, s2, 24576); }
    PHASE_SYNC();
    QUAD(a4, b2, 4, 2);
    __builtin_amdgcn_s_setprio(0);
    __builtin_amdgcn_sched_barrier(0);
    if (full) asm volatile("s_waitcnt vmcnt(8)" ::: "memory");
    else      asm volatile("s_waitcnt vmcnt(0)" ::: "memory");
    __builtin_amdgcn_s_barrier();

    // ================= K-step 2i+1 (buf1, byte 65536) =================
    // P5: read av0-3 + bv0-1 (12 ds_read)
#pragma unroll
    for (int mi = 0; mi < 4; ++mi) {
      a0[mi][0] = *(const bf16x8*)(ldsc + 65536 + avbase + mi * 2048 + offk0);
      a0[mi][1] = *(const bf16x8*)(ldsc + 65536 + avbase + mi * 2048 + offk1);
    }
#pragma unroll
    for (int ni = 0; ni < 2; ++ni) {
      b0[ni][0] = *(const bf16x8*)(ldsc + 65536 + bvbase + ni * 2048 + offk0);
      b0[ni][1] = *(const bf16x8*)(ldsc + 65536 + bvbase + ni * 2048 + offk1);
    }
    PHASE_SYNC();
    QUAD(a0, b0, 0, 0);
    PHASE_END();

    // P6: read av4-7 + bv2-3 (12 ds_read)
#pragma unroll
    for (int mi = 0; mi < 4; ++mi) {
      a4[mi][0] = *(const bf16x8*)(ldsc + 65536 + avbase + (4 + mi) * 2048 + offk0);
      a4[mi][1] = *(const bf16x8*)(ldsc + 65536 + avbase + (4 + mi) * 2048 + offk1);
    }
#pragma unroll
    for (int ni = 0; ni < 2; ++ni) {
      b2[ni][0] = *(const bf16x8*)(ldsc + 65536 + bvbase + (2 + ni) * 2048 + offk0);
      b2[ni][1] = *(const bf16x8*)(ldsc + 65536 + bvbase + (2 + ni) * 2048 + offk1);
    }
    PHASE_SYNC();
    QUAD(a0, b2, 0, 2);
    PHASE_END();

    // P7: stage s3:A0,A1 -> buf1 (regions last read in P6)
    if (full) { STAGE(Ab, s3, 32768); STAGE(Ab1, s3, 40960); }
    PHASE_SYNC();
    QUAD(a4, b0, 4, 0);
    PHASE_END();

    // P8: stage s3:B0,B1 -> buf1; counted vmcnt(8) retires s2 (P3/P4)
    if (full) { STAGE(Bb, s3, 49152); STAGE(Bb1, s3, 57344); }
    PHASE_SYNC();
    QUAD(a4, b2, 4, 2);
    __builtin_amdgcn_s_setprio(0);
    __builtin_amdgcn_sched_barrier(0);
    if (full) asm volatile("s_waitcnt vmcnt(8)" ::: "memory");
    else      asm volatile("s_waitcnt vmcnt(0)" ::: "memory");
    __builtin_amdgcn_s_barrier();
  }

  // epilogue: C/D layout (16x16x32 bf16): col = lane&15, row = (lane>>4)*4 + r
  int crow0 = brow * BM + wm * 128;
  int ccol0 = bcol * BN + wn * 64;
#pragma unroll
  for (int mi = 0; mi < 8; ++mi)
#pragma unroll
    for (int ni = 0; ni < 4; ++ni) {
      int col = ccol0 + ni * 16 + lrow;
#pragma unroll
      for (int r = 0; r < 4; ++r) {
        int row = crow0 + mi * 16 + lkhi * 4 + r;
        C[(size_t)row * GN + col] = acc[mi][ni][r];
      }
    }
}

// -------------------- fused out_scale/bias + LayerNorm (in place) --------------------
__global__ __launch_bounds__(256) void ln_fuse(
    float* __restrict__ h, const float* __restrict__ os,
    const float* __restrict__ bs, const float* __restrict__ g,
    const float* __restrict__ be) {
  constexpr int N = GN;  // 4096
  int row = blockIdx.x;
  float* hr = h + (size_t)row * N;
  int t = threadIdx.x;

  float v[16];
  float sum = 0.f, ssq = 0.f;
#pragma unroll
  for (int c = 0; c < 4; ++c) {
    int idx = c * 1024 + t * 4;
    float4 hv = *(const float4*)(hr + idx);
    float4 sv = *(const float4*)(os + idx);
    float4 bv = *(const float4*)(bs + idx);
    float a0 = hv.x * sv.x + bv.x;
    float a1 = hv.y * sv.y + bv.y;
    float a2 = hv.z * sv.z + bv.z;
    float a3 = hv.w * sv.w + bv.w;
    v[c * 4 + 0] = a0; v[c * 4 + 1] = a1; v[c * 4 + 2] = a2; v[c * 4 + 3] = a3;
    sum += a0 + a1 + a2 + a3;
    ssq += a0 * a0 + a1 * a1 + a2 * a2 + a3 * a3;
  }

  // wave64 reduce
#pragma unroll
  for (int off = 32; off > 0; off >>= 1) {
    sum += __shfl_down(sum, off);
    ssq += __shfl_down(ssq, off);
  }
  __shared__ float rs[8];
  int wid = t >> 6, lane = t & 63;
  if (lane == 0) { rs[wid] = sum; rs[4 + wid] = ssq; }
  __syncthreads();
  sum = rs[0] + rs[1] + rs[2] + rs[3];
  ssq = rs[4] + rs[5] + rs[6] + rs[7];

  float mean = sum * (1.f / N);
  float var = ssq * (1.f / N) - mean * mean;
  float rstd = rsqrtf(var + 1e-5f);

#pragma unroll
  for (int c = 0; c < 4; ++c) {
    int idx = c * 1024 + t * 4;
    float4 gv = *(const float4*)(g + idx);
    float4 bev = *(const float4*)(be + idx);
    float4 o;
    o.x = (v[c * 4 + 0] - mean) * rstd * gv.x + bev.x;
    o.y = (v[c * 4 + 1] - mean) * rstd * gv.y + bev.y;
    o.z = (v[c * 4 + 2] - mean) * rstd * gv.z + bev.z;
    o.w = (v[c * 4 + 3] - mean) * rstd * gv.w + bev.w;
    *(float4*)(hr + idx) = o;
  }
}

extern "C" void kernel_launch(void* const* d_in, const int* in_sizes, int n_in,
                              void* d_out, int out_size, void* d_ws, size_t ws_size,
                              hipStream_t stream) {
  const float* x      = (const float*)d_in[0];  // [4,2048,4096]
  const float* w      = (const float*)d_in[1];  // [4096,4096]
  const float* iscale = (const float*)d_in[2];  // [4096]
  const float* oscale = (const float*)d_in[3];  // [4096]
  const float* bias   = (const float*)d_in[4];  // [4096]
  const float* gamma  = (const float*)d_in[5];  // [4096]
  const float* beta   = (const float*)d_in[6];  // [4096]
  float* out = (float*)d_out;                   // [8192,4096] f32

  __bf16* Abf = (__bf16*)d_ws;                                   // 67 MB
  __bf16* Wbf = (__bf16*)((char*)d_ws + (size_t)GM * GK * 2);    // 33.5 MB

  // allow >64KB dynamic LDS (idempotent; immediate API, not graph-captured)
  (void)hipFuncSetAttribute((const void*)gemm_bt,
                            hipFuncAttributeMaxDynamicSharedMemorySize, LDS_BYTES);

  prep_x_kernel<<<(GM * GK) / (256 * 8), 256, 0, stream>>>(x, iscale, Abf);
  prep_w_kernel<<<(GN * GK) / (256 * 8), 256, 0, stream>>>(w, Wbf);
  gemm_bt<<<(GM / BM) * (GN / BN), 512, LDS_BYTES, stream>>>(Abf, Wbf, out);
  ln_fuse<<<GM, 256, 0, stream>>>(out, oscale, bias, gamma, beta);
}